// Round 3
// baseline (37349.036 us; speedup 1.0000x reference)
//
#include <hip/hip_runtime.h>
#include <math.h>

#define E 512
#define S_MAX 32
#define BATCH 32
#define HEADS 8
#define DH 64
#define HID 2048
#define VOCAB 30000

typedef unsigned short u16;
typedef __attribute__((ext_vector_type(8))) short short8;
typedef __attribute__((ext_vector_type(4))) float f32x4;

// ---------- bf16 split helpers (RNE) ----------
__device__ __forceinline__ u16 f2bf(float x) {
    union { float f; unsigned u; } v; v.f = x;
    unsigned r = v.u + 0x7fffu + ((v.u >> 16) & 1u);
    return (u16)(r >> 16);
}
__device__ __forceinline__ float bf2f(u16 h) {
    union { unsigned u; float f; } v; v.u = ((unsigned)h) << 16;
    return v.f;
}
__device__ __forceinline__ void split3(float x, u16& h, u16& m, u16& l) {
    h = f2bf(x); float hf = bf2f(h);
    float r1 = x - hf;
    m = f2bf(r1); float mf = bf2f(m);
    l = f2bf(r1 - mf);
}

// ---------------- positional encoding ----------------
__global__ void pe_kernel(float* __restrict__ PEp) {
    int s = blockIdx.x;
    for (int e = threadIdx.x; e < E; e += 256) {
        float expo = (float)(e & ~1) / (float)E;
        float den = powf(10000.0f, expo);
        float ang = (float)s / den;
        PEp[s * E + e] = (e & 1) ? cosf(ang) : sinf(ang);
    }
}

// ---------------- x = Ybuf + pe, also emit bf16x3 planes ----------------
__global__ void build_x_kernel(float* __restrict__ X, const float* __restrict__ Ybuf,
                               const float* __restrict__ PEp, int Seff,
                               u16* __restrict__ Xh, u16* __restrict__ Xm, u16* __restrict__ Xl) {
    long idx = (long)blockIdx.x * 256 + threadIdx.x;
    long total = (long)BATCH * Seff * E;
    if (idx >= total) return;
    int e = (int)(idx & (E - 1));
    long mm = idx >> 9;
    int b = (int)(mm / Seff);
    int s = (int)(mm - (long)b * Seff);
    float v = Ybuf[((long)b * S_MAX + s) * E + e] + PEp[s * E + e];
    X[idx] = v;
    u16 h, m, l; split3(v, h, m, l);
    Xh[idx] = h; Xm[idx] = m; Xl[idx] = l;
}

// ---------------- elementwise f32 -> bf16x3 planes (noise) ----------------
__global__ void split_act_kernel(const float* __restrict__ in, long n,
                                 u16* __restrict__ Ph, u16* __restrict__ Pm, u16* __restrict__ Pl) {
    long i = ((long)blockIdx.x * 256 + threadIdx.x) * 4;
    if (i >= n) return;
    float4 v = *(const float4*)(in + i);
    u16 h, m, l;
    split3(v.x, h, m, l); Ph[i] = h; Pm[i] = m; Pl[i] = l;
    split3(v.y, h, m, l); Ph[i+1] = h; Pm[i+1] = m; Pl[i+1] = l;
    split3(v.z, h, m, l); Ph[i+2] = h; Pm[i+2] = m; Pl[i+2] = l;
    split3(v.w, h, m, l); Ph[i+3] = h; Pm[i+3] = m; Pl[i+3] = l;
}

// ---------------- weight split + transpose: W f32 [K][N] -> 3 bf16 planes [N][K] ----------------
__global__ __launch_bounds__(256) void wsplit_kernel(const float* __restrict__ W,
                                                     u16* __restrict__ Ph, u16* __restrict__ Pm,
                                                     u16* __restrict__ Pl,
                                                     int K, int N, long wzin, long wzout) {
    int z = blockIdx.z;
    W += (long)z * wzin; Ph += (long)z * wzout; Pm += (long)z * wzout; Pl += (long)z * wzout;
    int n0 = blockIdx.x * 32, k0 = blockIdx.y * 32;
    __shared__ float T[32][33];
    int tid = threadIdx.x;
    int kk = tid >> 3, nn = (tid & 7) * 4;
    float4 v = *(const float4*)&W[(long)(k0 + kk) * N + n0 + nn];
    T[kk][nn + 0] = v.x; T[kk][nn + 1] = v.y; T[kk][nn + 2] = v.z; T[kk][nn + 3] = v.w;
    __syncthreads();
    int n = tid >> 3, k4 = (tid & 7) * 4;
    u16 h[4], m[4], l[4];
#pragma unroll
    for (int j = 0; j < 4; j++) split3(T[k4 + j][n], h[j], m[j], l[j]);
    long o = (long)(n0 + n) * K + k0 + k4;
    *(ushort4*)&Ph[o] = make_ushort4(h[0], h[1], h[2], h[3]);
    *(ushort4*)&Pm[o] = make_ushort4(m[0], m[1], m[2], m[3]);
    *(ushort4*)&Pl[o] = make_ushort4(l[0], l[1], l[2], l[3]);
}

// ---------------- MFMA bf16x3-split GEMM ----------------
// C(MxN) = A(MxK) * W(KxN) + bias ; A planes [M][K], W planes [N][K] (pre-transposed)
// 64x64 tile, 4 waves (2x2), each wave 32x32 = 2x2 frags of 16x16, K-step 32.
// 6 split products: (0,0)(0,1)(1,0)(1,1)(0,2)(2,0) accumulated in f32.
template <int RELU, int WF32, int WSPLIT>
__global__ __launch_bounds__(256) void gemm_mfma(
    const u16* __restrict__ Ah, const u16* __restrict__ Am, const u16* __restrict__ Al,
    const u16* __restrict__ Wh, const u16* __restrict__ Wm, const u16* __restrict__ Wl,
    const float* __restrict__ bias,
    float* __restrict__ C, u16* __restrict__ Ch, u16* __restrict__ Cm, u16* __restrict__ Cl,
    int M, int N, int K, long wz, long cz, long bz) {
    int z = blockIdx.z;
    const u16* Ap[3] = {Ah, Am, Al};
    const u16* Bp[3] = {Wh + (long)z * wz, Wm + (long)z * wz, Wl + (long)z * wz};
    bias += (long)z * bz;
    C += (long)z * cz;
    Ch += (long)z * cz; Cm += (long)z * cz; Cl += (long)z * cz;

    int n0 = blockIdx.x * 64, m0 = blockIdx.y * 64;
    int tid = threadIdx.x, lane = tid & 63, wid = tid >> 6;
    int wr = wid >> 1, wc = wid & 1;

    __shared__ u16 As[3][2048];
    __shared__ u16 Bs[3][2048];

    // staging: LDS-linear dest (thread t -> elem t*8); decode global src accordingly
    int srow = (tid >> 6) * 16 + (tid & 15);
    int scol = ((tid >> 4) & 3) * 8;
    int arow = m0 + srow; if (arow >= M) arow = M - 1;
    int brow = n0 + srow;
    long abase = (long)arow * K + scol;
    long bbase = (long)brow * K + scol;

    uint4 ra[3], rb[3];
#pragma unroll
    for (int p = 0; p < 3; p++) {
        ra[p] = *(const uint4*)(Ap[p] + abase);
        rb[p] = *(const uint4*)(Bp[p] + bbase);
    }

    f32x4 acc[2][2];
#pragma unroll
    for (int mi = 0; mi < 2; mi++)
#pragma unroll
        for (int ni = 0; ni < 2; ni++) acc[mi][ni] = (f32x4){0.f, 0.f, 0.f, 0.f};

    int fro = (lane >> 4) * 128 + (lane & 15) * 8;
    const int PA[6] = {0, 0, 1, 1, 0, 2};
    const int PB[6] = {0, 1, 0, 1, 2, 0};

    for (int k0 = 0; k0 < K; k0 += 32) {
#pragma unroll
        for (int p = 0; p < 3; p++) {
            *(uint4*)&As[p][tid * 8] = ra[p];
            *(uint4*)&Bs[p][tid * 8] = rb[p];
        }
        __syncthreads();
        if (k0 + 32 < K) {
#pragma unroll
            for (int p = 0; p < 3; p++) {
                ra[p] = *(const uint4*)(Ap[p] + abase + k0 + 32);
                rb[p] = *(const uint4*)(Bp[p] + bbase + k0 + 32);
            }
        }
        short8 af[3][2], bf[3][2];
#pragma unroll
        for (int p = 0; p < 3; p++) {
#pragma unroll
            for (int q = 0; q < 2; q++) {
                af[p][q] = *(const short8*)&As[p][(wr * 2 + q) * 512 + fro];
                bf[p][q] = *(const short8*)&Bs[p][(wc * 2 + q) * 512 + fro];
            }
        }
#pragma unroll
        for (int u = 0; u < 6; u++) {
#pragma unroll
            for (int mi = 0; mi < 2; mi++)
#pragma unroll
                for (int ni = 0; ni < 2; ni++)
                    acc[mi][ni] = __builtin_amdgcn_mfma_f32_16x16x32_bf16(
                        af[PA[u]][mi], bf[PB[u]][ni], acc[mi][ni], 0, 0, 0);
        }
        __syncthreads();
    }

    // epilogue: D col = lane&15, row = (lane>>4)*4 + reg  [m89-verified]
#pragma unroll
    for (int mi = 0; mi < 2; mi++) {
#pragma unroll
        for (int ni = 0; ni < 2; ni++) {
            int col = n0 + wc * 32 + ni * 16 + (lane & 15);
            float bv = bias[col];
#pragma unroll
            for (int j = 0; j < 4; j++) {
                int row = m0 + wr * 32 + mi * 16 + (lane >> 4) * 4 + j;
                if (row < M) {
                    float v = acc[mi][ni][j] + bv;
                    if (RELU) v = fmaxf(v, 0.f);
                    long idx = (long)row * N + col;
                    if (WF32) C[idx] = v;
                    if (WSPLIT) {
                        u16 hh, mm, ll; split3(v, hh, mm, ll);
                        Ch[idx] = hh; Cm[idx] = mm; Cl[idx] = ll;
                    }
                }
            }
        }
    }
}

// ---------------- attention: one (q-row, head, batch) per 64-thread block ----------------
__global__ __launch_bounds__(64) void attn_kernel(const float* __restrict__ Q,
                                                  const float* __restrict__ Kp,
                                                  const float* __restrict__ Vp,
                                                  u16* __restrict__ Oh, u16* __restrict__ Om,
                                                  u16* __restrict__ Ol,
                                                  int Seff, int kvBatchStride) {
    int s = blockIdx.x, h = blockIdx.y, b = blockIdx.z;
    int lane = threadIdx.x;
    __shared__ float qs[DH];
    qs[lane] = Q[((long)(b * Seff + s)) * E + h * DH + lane];
    __syncthreads();

    float sc = -INFINITY;
    if (lane < Seff) {
        const float4* k4 = (const float4*)(Kp + (long)b * kvBatchStride + (long)lane * E + h * DH);
        const float4* q4 = (const float4*)qs;
        float acc = 0.f;
#pragma unroll
        for (int d = 0; d < DH / 4; d++) {
            float4 kv = k4[d];
            float4 qv = q4[d];
            acc += qv.x * kv.x; acc += qv.y * kv.y; acc += qv.z * kv.z; acc += qv.w * kv.w;
        }
        sc = acc * 0.125f;
    }
    float m = sc;
#pragma unroll
    for (int off = 32; off; off >>= 1) m = fmaxf(m, __shfl_xor(m, off));
    float p = (lane < Seff) ? expf(sc - m) : 0.f;
    float sum = p;
#pragma unroll
    for (int off = 32; off; off >>= 1) sum += __shfl_xor(sum, off);
    p = p / sum;

    float acc = 0.f;
    const float* vbase = Vp + (long)b * kvBatchStride + h * DH + lane;
    for (int k = 0; k < Seff; k++) {
        float pk = __shfl(p, k);
        acc = fmaf(pk, vbase[(long)k * E], acc);
    }
    long o = ((long)(b * Seff + s)) * E + h * DH + lane;
    u16 hh, mm, ll; split3(acc, hh, mm, ll);
    Oh[o] = hh; Om[o] = mm; Ol[o] = ll;
}

// ---------------- x = LN(x + delta), also emit splits ----------------
__global__ __launch_bounds__(64) void resid_ln_kernel(float* __restrict__ X,
                                                      const float* __restrict__ Dlt,
                                                      const float* __restrict__ g,
                                                      const float* __restrict__ bb,
                                                      u16* __restrict__ Xh, u16* __restrict__ Xm,
                                                      u16* __restrict__ Xl) {
    long row = blockIdx.x;
    int lane = threadIdx.x;
    float* xr = X + row * E;
    const float* dr = Dlt + row * E;
    float v[8];
    float s = 0.f;
#pragma unroll
    for (int i = 0; i < 8; i++) {
        int e = lane + i * 64;
        v[i] = xr[e] + dr[e];
        s += v[i];
    }
#pragma unroll
    for (int off = 32; off; off >>= 1) s += __shfl_xor(s, off);
    float mean = s * (1.0f / E);
    float sq = 0.f;
#pragma unroll
    for (int i = 0; i < 8; i++) {
        float d = v[i] - mean;
        sq += d * d;
    }
#pragma unroll
    for (int off = 32; off; off >>= 1) sq += __shfl_xor(sq, off);
    float var = sq * (1.0f / E);
    float r = 1.0f / sqrtf(var + 1e-5f);
#pragma unroll
    for (int i = 0; i < 8; i++) {
        int e = lane + i * 64;
        float o = (v[i] - mean) * r * g[e] + bb[e];
        xr[e] = o;
        u16 hh, mm, ll; split3(o, hh, mm, ll);
        long idx = row * E + e;
        Xh[idx] = hh; Xm[idx] = mm; Xl[idx] = ll;
    }
}

// ---------------- logits = tok(B x E) @ soft_W(E x V) + soft_b ----------------
__global__ __launch_bounds__(256) void logits_kernel(const float* __restrict__ X,
                                                     const float* __restrict__ SW,
                                                     const float* __restrict__ sb,
                                                     float* __restrict__ Lg,
                                                     int Seff, int t) {
    int nl = threadIdx.x & 63;
    int kq = threadIdx.x >> 6;
    int n = blockIdx.x * 64 + nl;
    bool nok = n < VOCAB;
    float acc[BATCH];
#pragma unroll
    for (int b = 0; b < BATCH; b++) acc[b] = 0.f;
    if (nok) {
        int k0 = kq * 128;
        for (int k = k0; k < k0 + 128; k++) {
            float wv = SW[(long)k * VOCAB + n];
#pragma unroll
            for (int b = 0; b < BATCH; b++) {
                acc[b] = fmaf(X[((long)(b * Seff + t)) * E + k], wv, acc[b]);
            }
        }
    }
    __shared__ float red[4][64];
    for (int b = 0; b < BATCH; b++) {
        red[kq][nl] = acc[b];
        __syncthreads();
        if (kq == 0 && nok) {
            float sum = red[0][nl] + red[1][nl] + red[2][nl] + red[3][nl] + sb[n];
            Lg[(long)b * VOCAB + n] = sum;
        }
        __syncthreads();
    }
}

// ---------------- softmax -> out[:,t,:], argmax -> Ybuf[:,t,:] = w2v[idx] ----------------
__global__ __launch_bounds__(256) void softmax_out_kernel(const float* __restrict__ Lg,
                                                          float* __restrict__ Out,
                                                          const float* __restrict__ w2v,
                                                          float* __restrict__ Ybuf, int t) {
    int b = blockIdx.x;
    int tid = threadIdx.x;
    const float* lb = Lg + (long)b * VOCAB;
    __shared__ float red[256];

    float m = -INFINITY;
    for (int n = tid; n < VOCAB; n += 256) m = fmaxf(m, lb[n]);
    red[tid] = m;
    __syncthreads();
    for (int off = 128; off; off >>= 1) {
        if (tid < off) red[tid] = fmaxf(red[tid], red[tid + off]);
        __syncthreads();
    }
    m = red[0];
    __syncthreads();

    float s = 0.f;
    for (int n = tid; n < VOCAB; n += 256) s += expf(lb[n] - m);
    red[tid] = s;
    __syncthreads();
    for (int off = 128; off; off >>= 1) {
        if (tid < off) red[tid] += red[tid + off];
        __syncthreads();
    }
    s = red[0];
    __syncthreads();

    float bestv = -1.0f;
    int besti = VOCAB;
    float* ob = Out + ((long)b * S_MAX + t) * VOCAB;
    for (int n = tid; n < VOCAB; n += 256) {
        float p = expf(lb[n] - m) / s;
        ob[n] = p;
        if (p > bestv) { bestv = p; besti = n; }
    }
    __shared__ float rv[256];
    __shared__ int ri[256];
    rv[tid] = bestv;
    ri[tid] = besti;
    __syncthreads();
    for (int off = 128; off; off >>= 1) {
        if (tid < off) {
            float v2 = rv[tid + off];
            int i2 = ri[tid + off];
            if (v2 > rv[tid] || (v2 == rv[tid] && i2 < ri[tid])) { rv[tid] = v2; ri[tid] = i2; }
        }
        __syncthreads();
    }
    int idx = ri[0];
    float* yb = Ybuf + ((long)b * S_MAX + t) * E;
    for (int e = tid; e < E; e += 256) yb[e] = w2v[(long)idx * E + e];
}

// =====================================================================
extern "C" void kernel_launch(void* const* d_in, const int* in_sizes, int n_in,
                              void* d_out, int out_size, void* d_ws, size_t ws_size,
                              hipStream_t stream) {
    const float* noise    = (const float*)d_in[0];
    const float* seeds    = (const float*)d_in[1];
    const float* inemb_W  = (const float*)d_in[2];
    const float* inemb_b  = (const float*)d_in[3];
    const float* g_attn_W = (const float*)d_in[4];
    const float* g_attn_b = (const float*)d_in[5];
    const float* g_cross_W= (const float*)d_in[6];
    const float* g_cross_b= (const float*)d_in[7];
    const float* g_ffn_W1 = (const float*)d_in[8];
    const float* g_ffn_b1 = (const float*)d_in[9];
    const float* g_ffn_W2 = (const float*)d_in[10];
    const float* g_ffn_b2 = (const float*)d_in[11];
    const float* g_ln_g   = (const float*)d_in[12];
    const float* g_ln_b   = (const float*)d_in[13];
    const float* o_attn_W = (const float*)d_in[14];
    const float* o_attn_b = (const float*)d_in[15];
    const float* o_ffn_W1 = (const float*)d_in[16];
    const float* o_ffn_b1 = (const float*)d_in[17];
    const float* o_ffn_W2 = (const float*)d_in[18];
    const float* o_ffn_b2 = (const float*)d_in[19];
    const float* o_ln_g   = (const float*)d_in[20];
    const float* o_ln_b   = (const float*)d_in[21];
    const float* w2v      = (const float*)d_in[22];
    const float* soft_W   = (const float*)d_in[23];
    const float* soft_b   = (const float*)d_in[24];
    float* out = (float*)d_out;
    float* ws = (float*)d_ws;

    const long EE  = (long)E * E;                 // 262144
    const long EH  = (long)E * HID;               // 1048576
    const long BSE = (long)BATCH * S_MAX * E;     // 524288
    const long BSH = (long)BATCH * S_MAX * HID;   // 2097152
    const long WTOT = 46 * EE;                    // 12058624 elems per plane (full split)

    // ---- workspace layout (f32 words) ----
    long off = 0;
    float* PE   = ws + off; off += 16384;
    float* YBUF = ws + off; off += BSE;
    float* X    = ws + off; off += BSE;
    float* TMP  = ws + off; off += BSE;
    float* QKV  = ws + off; off += 3 * BSE;
    float* KWVW = ws + off; off += 4 * BSE;
    float* LG   = ws + off; off += 960000;
    u16* XsH = (u16*)(ws + off); off += 3 * BSE / 2;
    u16* XsM = XsH + BSE; u16* XsL = XsM + BSE;
    u16* AOH = (u16*)(ws + off); off += 3 * BSE / 2;
    u16* AOM = AOH + BSE; u16* AOL = AOM + BSE;
    u16* HBH = (u16*)(ws + off); off += 3 * BSH / 2;
    u16* HBM2 = HBH + BSH; u16* HBL = HBM2 + BSH;
    long baseWords = off;

    bool full = ws_size >= (size_t)(baseWords + 3 * WTOT / 2) * 4;
    long WT_ELEMS = full ? WTOT : 4 * EE;
    u16* WT_H = (u16*)(ws + baseWords);
    u16* WT_M = WT_H + WT_ELEMS;
    u16* WT_L = WT_M + WT_ELEMS;

    // weight-plane offsets (full mode)
    const long OFF_INEMB = 0;
    const long OFF_GATTN = 2 * EE;
    const long OFF_GCROSS = 10 * EE;
    const long OFF_OATTN = 18 * EE;
    const long OFF_GF1 = 22 * EE;
    const long OFF_GF2 = 30 * EE;
    const long OFF_OF1 = 38 * EE;
    const long OFF_OF2 = 42 * EE;

    // split (fallback: on demand) ; returns plane offset to use
    auto WSPL = [&](const float* Wsrc, long offFull, int K, int N, int z) -> long {
        if (full) return offFull;
        wsplit_kernel<<<dim3(N / 32, K / 32, z), dim3(256), 0, stream>>>(
            Wsrc, WT_H, WT_M, WT_L, K, N, (long)K * N, (long)K * N);
        return 0;
    };

    // mode: 0 = f32 out, 1 = split out, 2 = relu + split out
    auto GEMM = [&](const u16* Ah, const u16* Am, const u16* Al, long woff,
                    const float* bias, float* C, u16* Ch, u16* Cm, u16* Cl,
                    int M, int N, int K, int Z, long wz, long cz, long bz, int mode) {
        dim3 g(N / 64, (M + 63) / 64, Z);
        const u16* Wh = WT_H + woff; const u16* Wm = WT_M + woff; const u16* Wl = WT_L + woff;
        if (mode == 0)
            gemm_mfma<0, 1, 0><<<g, dim3(256), 0, stream>>>(Ah, Am, Al, Wh, Wm, Wl, bias,
                                                            C, Ch, Cm, Cl, M, N, K, wz, cz, bz);
        else if (mode == 1)
            gemm_mfma<0, 0, 1><<<g, dim3(256), 0, stream>>>(Ah, Am, Al, Wh, Wm, Wl, bias,
                                                            C, Ch, Cm, Cl, M, N, K, wz, cz, bz);
        else
            gemm_mfma<1, 0, 1><<<g, dim3(256), 0, stream>>>(Ah, Am, Al, Wh, Wm, Wl, bias,
                                                            C, Ch, Cm, Cl, M, N, K, wz, cz, bz);
    };

    // ---- preamble ----
    pe_kernel<<<dim3(S_MAX), dim3(256), 0, stream>>>(PE);
    hipMemcpyAsync(YBUF, seeds, BSE * sizeof(float), hipMemcpyDeviceToDevice, stream);

    if (full) {
        wsplit_kernel<<<dim3(16, 16, 2), dim3(256), 0, stream>>>(inemb_W, WT_H + OFF_INEMB, WT_M + OFF_INEMB, WT_L + OFF_INEMB, 512, 512, EE, EE);
        wsplit_kernel<<<dim3(16, 16, 8), dim3(256), 0, stream>>>(g_attn_W, WT_H + OFF_GATTN, WT_M + OFF_GATTN, WT_L + OFF_GATTN, 512, 512, EE, EE);
        wsplit_kernel<<<dim3(16, 16, 8), dim3(256), 0, stream>>>(g_cross_W, WT_H + OFF_GCROSS, WT_M + OFF_GCROSS, WT_L + OFF_GCROSS, 512, 512, EE, EE);
        wsplit_kernel<<<dim3(16, 16, 4), dim3(256), 0, stream>>>(o_attn_W, WT_H + OFF_OATTN, WT_M + OFF_OATTN, WT_L + OFF_OATTN, 512, 512, EE, EE);
        wsplit_kernel<<<dim3(64, 16, 2), dim3(256), 0, stream>>>(g_ffn_W1, WT_H + OFF_GF1, WT_M + OFF_GF1, WT_L + OFF_GF1, 512, 2048, EH, EH);
        wsplit_kernel<<<dim3(16, 64, 2), dim3(256), 0, stream>>>(g_ffn_W2, WT_H + OFF_GF2, WT_M + OFF_GF2, WT_L + OFF_GF2, 2048, 512, EH, EH);
        wsplit_kernel<<<dim3(64, 16, 1), dim3(256), 0, stream>>>(o_ffn_W1, WT_H + OFF_OF1, WT_M + OFF_OF1, WT_L + OFF_OF1, 512, 2048, EH, EH);
        wsplit_kernel<<<dim3(16, 64, 1), dim3(256), 0, stream>>>(o_ffn_W2, WT_H + OFF_OF2, WT_M + OFF_OF2, WT_L + OFF_OF2, 2048, 512, EH, EH);
    }

    // noise splits (into HB planes, free until step 0's FFN1)
    split_act_kernel<<<dim3((int)(BSE / 1024)), dim3(256), 0, stream>>>(noise, BSE, HBH, HBM2, HBL);

    // inemb: two chained E x E GEMMs -> WEMB splits (in Xs planes)
    {
        long w = WSPL(inemb_W, OFF_INEMB, 512, 512, 1);
        GEMM(HBH, HBM2, HBL, w, inemb_b, TMP, AOH, AOM, AOL, BATCH * S_MAX, E, E, 1, 0, 0, 0, 1);
        w = WSPL(inemb_W + EE, OFF_INEMB + EE, 512, 512, 1);
        GEMM(AOH, AOM, AOL, w, inemb_b + E, TMP, XsH, XsM, XsL, BATCH * S_MAX, E, E, 1, 0, 0, 0, 1);
    }
    // cross K/V from constant w (full-S, f32 out)
    for (int i = 0; i < 2; i++) {
        long w = WSPL(g_cross_W + (i * 4 + 1) * EE, OFF_GCROSS + (i * 4 + 1) * EE, 512, 512, 2);
        GEMM(XsH, XsM, XsL, w, g_cross_b + (i * 4 + 1) * E, KWVW + i * 2 * BSE, AOH, AOM, AOL,
             BATCH * S_MAX, E, E, 2, EE, BSE, E, 0);
    }

    // ---- autoregressive scan ----
    for (int t = 0; t < S_MAX; t++) {
        int Seff = t + 1;
        int Mrows = BATCH * Seff;
        long ME = (long)Mrows * E;
        int total = Mrows * E;

        build_x_kernel<<<dim3((total + 255) / 256), dim3(256), 0, stream>>>(X, YBUF, PE, Seff,
                                                                            XsH, XsM, XsL);

        for (int i = 0; i < 2; i++) {
            // self-attn
            long w = WSPL(g_attn_W + (long)i * 4 * EE, OFF_GATTN + i * 4 * EE, 512, 512, 3);
            GEMM(XsH, XsM, XsL, w, g_attn_b + (long)i * 4 * E, QKV, AOH, AOM, AOL,
                 Mrows, E, E, 3, EE, ME, E, 0);
            attn_kernel<<<dim3(Seff, HEADS, BATCH), dim3(64), 0, stream>>>(
                QKV, QKV + ME, QKV + 2 * ME, AOH, AOM, AOL, Seff, Seff * E);
            w = WSPL(g_attn_W + (i * 4 + 3) * EE, OFF_GATTN + (i * 4 + 3) * EE, 512, 512, 1);
            GEMM(AOH, AOM, AOL, w, g_attn_b + (i * 4 + 3) * E, TMP, AOH, AOM, AOL,
                 Mrows, E, E, 1, 0, 0, 0, 0);
            resid_ln_kernel<<<dim3(Mrows), dim3(64), 0, stream>>>(
                X, TMP, g_ln_g + (i * 3 + 0) * E, g_ln_b + (i * 3 + 0) * E, XsH, XsM, XsL);
            // cross-attn
            w = WSPL(g_cross_W + (long)i * 4 * EE, OFF_GCROSS + i * 4 * EE, 512, 512, 1);
            GEMM(XsH, XsM, XsL, w, g_cross_b + (long)i * 4 * E, QKV, AOH, AOM, AOL,
                 Mrows, E, E, 1, 0, 0, 0, 0);
            attn_kernel<<<dim3(Seff, HEADS, BATCH), dim3(64), 0, stream>>>(
                QKV, KWVW + i * 2 * BSE, KWVW + i * 2 * BSE + BSE, AOH, AOM, AOL, Seff, S_MAX * E);
            w = WSPL(g_cross_W + (i * 4 + 3) * EE, OFF_GCROSS + (i * 4 + 3) * EE, 512, 512, 1);
            GEMM(AOH, AOM, AOL, w, g_cross_b + (i * 4 + 3) * E, TMP, AOH, AOM, AOL,
                 Mrows, E, E, 1, 0, 0, 0, 0);
            resid_ln_kernel<<<dim3(Mrows), dim3(64), 0, stream>>>(
                X, TMP, g_ln_g + (i * 3 + 1) * E, g_ln_b + (i * 3 + 1) * E, XsH, XsM, XsL);
            // FFN
            w = WSPL(g_ffn_W1 + (long)i * EH, OFF_GF1 + i * EH, 512, 2048, 1);
            GEMM(XsH, XsM, XsL, w, g_ffn_b1 + (long)i * HID, TMP, HBH, HBM2, HBL,
                 Mrows, HID, E, 1, 0, 0, 0, 2);
            w = WSPL(g_ffn_W2 + (long)i * EH, OFF_GF2 + i * EH, 2048, 512, 1);
            GEMM(HBH, HBM2, HBL, w, g_ffn_b2 + (long)i * E, TMP, AOH, AOM, AOL,
                 Mrows, E, HID, 1, 0, 0, 0, 0);
            resid_ln_kernel<<<dim3(Mrows), dim3(64), 0, stream>>>(
                X, TMP, g_ln_g + (i * 3 + 2) * E, g_ln_b + (i * 3 + 2) * E, XsH, XsM, XsL);
        }
        // o block
        {
            long w = WSPL(o_attn_W, OFF_OATTN, 512, 512, 3);
            GEMM(XsH, XsM, XsL, w, o_attn_b, QKV, AOH, AOM, AOL, Mrows, E, E, 3, EE, ME, E, 0);
            attn_kernel<<<dim3(Seff, HEADS, BATCH), dim3(64), 0, stream>>>(
                QKV, QKV + ME, QKV + 2 * ME, AOH, AOM, AOL, Seff, Seff * E);
            w = WSPL(o_attn_W + 3 * EE, OFF_OATTN + 3 * EE, 512, 512, 1);
            GEMM(AOH, AOM, AOL, w, o_attn_b + 3 * E, TMP, AOH, AOM, AOL, Mrows, E, E, 1, 0, 0, 0, 0);
            resid_ln_kernel<<<dim3(Mrows), dim3(64), 0, stream>>>(X, TMP, o_ln_g, o_ln_b,
                                                                  XsH, XsM, XsL);
            w = WSPL(o_ffn_W1, OFF_OF1, 512, 2048, 1);
            GEMM(XsH, XsM, XsL, w, o_ffn_b1, TMP, HBH, HBM2, HBL, Mrows, HID, E, 1, 0, 0, 0, 2);
            w = WSPL(o_ffn_W2, OFF_OF2, 2048, 512, 1);
            GEMM(HBH, HBM2, HBL, w, o_ffn_b2, TMP, AOH, AOM, AOL, Mrows, E, HID, 1, 0, 0, 0, 0);
            resid_ln_kernel<<<dim3(Mrows), dim3(64), 0, stream>>>(X, TMP, o_ln_g + E, o_ln_b + E,
                                                                  XsH, XsM, XsL);
        }

        logits_kernel<<<dim3((VOCAB + 63) / 64), dim3(256), 0, stream>>>(X, soft_W, soft_b, LG, Seff, t);
        softmax_out_kernel<<<dim3(BATCH), dim3(256), 0, stream>>>(LG, out, w2v, YBUF, t);
    }
}